// Round 5
// baseline (1270.815 us; speedup 1.0000x reference)
//
#include <hip/hip_runtime.h>
#include <hip/hip_bf16.h>
#include <math.h>

// Problem constants
constexpr int B    = 16;
constexpr int H    = 96;
constexpr int W    = 96;
constexpr int C    = 512;
constexpr int D    = 64;
constexpr int NBH  = 24;          // blocks per side
constexpr int NB   = 576;         // num_block_tot
constexpr int HW   = 9216;
constexpr int TOPK = 16;
constexpr int TK2  = 32;          // 2*TOPK
constexpr int NCAND = 40;         // fp16-selection candidates before exact fp32 re-rank
constexpr int KC   = 384;         // OpenBLAS sgemm k-panel (Zen/Haswell SGEMM_DEFAULT_Q)

// ---------------------------------------------------------------- K0: transpose weights
__global__ void k_transpose(const float* __restrict__ Wk, const float* __restrict__ Wq,
                            float* __restrict__ WkT, float* __restrict__ WqT) {
    int idx = blockIdx.x * 256 + threadIdx.x;   // over C*D
    if (idx < C * D) {
        int c = idx >> 6, d = idx & 63;
        WkT[c * D + d] = Wk[d * C + c];
        WqT[c * D + d] = Wq[d * C + c];
    }
}

// ---------------------------------------------------------------- K1: pool + q + k, fp32 numpy-order
// mean: sequential 16 pixels (dy,dx) then /16; linears: fmaf chains SPLIT at KC=384 (OpenBLAS panels)
__global__ __launch_bounds__(256) void k_embed(
    const float* __restrict__ src,
    const float* __restrict__ WkT, const float* __restrict__ WqT,
    const float* __restrict__ bk,  const float* __restrict__ bq,
    float* __restrict__ k32, float* __restrict__ q32) {
    __shared__ float sS[16][C];    // 32 KB
    __shared__ float sE[C];        // 2 KB

    int t   = threadIdx.x;
    int blk = blockIdx.x;
    int b = blk / NB, n = blk % NB;
    int nh = n / NBH, nw = n % NBH;
    int y0 = nh * 4, x0 = nw * 4;

    for (int r = 0; r < 8; ++r) {
        int f4 = r * 256 + t;
        int px = f4 >> 7;
        int c4 = f4 & 127;
        int dy = px >> 2, dx = px & 3;
        const float4* g = (const float4*)(src + ((size_t)(b * H + y0 + dy) * W + (x0 + dx)) * C);
        ((float4*)sS[px])[c4] = g[c4];
    }
    __syncthreads();

    // block mean: strict sequential accumulation over (dy,dx) row-major, fp32, then /16
    for (int cc = t; cc < C; cc += 256) {
        float s = sS[0][cc];
        #pragma unroll
        for (int px = 1; px < 16; ++px) s += sS[px][cc];
        sE[cc] = s * 0.0625f;
    }
    __syncthreads();

    // k: thread (pg,d) -> 4 pixels; per pixel TWO fmaf chains (c<384, c>=384) added once
    int d = t & 63, pg = t >> 6;
    int px0 = pg * 4;
    float a0 = 0.f, a1 = 0.f, a2 = 0.f, a3 = 0.f;   // panel 0
    for (int cc = 0; cc < KC; ++cc) {
        float wk = WkT[cc * D + d];
        a0 = __builtin_fmaf(sS[px0 + 0][cc], wk, a0);
        a1 = __builtin_fmaf(sS[px0 + 1][cc], wk, a1);
        a2 = __builtin_fmaf(sS[px0 + 2][cc], wk, a2);
        a3 = __builtin_fmaf(sS[px0 + 3][cc], wk, a3);
    }
    float e0 = 0.f, e1 = 0.f, e2 = 0.f, e3 = 0.f;   // panel 1
    for (int cc = KC; cc < C; ++cc) {
        float wk = WkT[cc * D + d];
        e0 = __builtin_fmaf(sS[px0 + 0][cc], wk, e0);
        e1 = __builtin_fmaf(sS[px0 + 1][cc], wk, e1);
        e2 = __builtin_fmaf(sS[px0 + 2][cc], wk, e2);
        e3 = __builtin_fmaf(sS[px0 + 3][cc], wk, e3);
    }
    float bkd = bk[d];
    float kv0 = (a0 + e0) + bkd;
    float kv1 = (a1 + e1) + bkd;
    float kv2 = (a2 + e2) + bkd;
    float kv3 = (a3 + e3) + bkd;
    #pragma unroll
    for (int u = 0; u < 4; ++u) {
        int pxx = px0 + u;
        int dy = pxx >> 2, dx = pxx & 3;
        size_t p = (size_t)(y0 + dy) * W + (x0 + dx);
        float v = (u == 0 ? kv0 : u == 1 ? kv1 : u == 2 ? kv2 : kv3);
        k32[((size_t)b * HW + p) * D + d] = v;
    }

    // q: same split-chain per d (threads 0..63)
    if (t < 64) {
        float qa = 0.f;
        for (int cc = 0; cc < KC; ++cc)
            qa = __builtin_fmaf(sE[cc], WqT[cc * D + t], qa);
        float qe = 0.f;
        for (int cc = KC; cc < C; ++cc)
            qe = __builtin_fmaf(sE[cc], WqT[cc * D + t], qe);
        q32[((size_t)b * NB + n) * D + t] = (qa + qe) + bq[t];
    }
}

// ---------------------------------------------------------------- K2: scores, np.einsum SSE order
// per element: 4 lane accumulators over d%4, separate mul+add, reduce (L0+L1)+(L2+L3)
__global__ __launch_bounds__(256) void k_scores(
    const float* __restrict__ q32, const float* __restrict__ k32,
    _Float16* __restrict__ S16) {
    #pragma clang fp contract(off)
    __shared__ float sQ[32][68];   // +4 pad keeps float4 alignment, 4-way conflict max
    __shared__ float sK[32][68];

    int t  = threadIdx.x;
    int p0 = blockIdx.x * 32;      // 288 tiles
    int n0 = blockIdx.y * 32;      // 18 tiles
    int b  = blockIdx.z;
    int tx = t & 15, ty = t >> 4;

    const float* qb = q32 + ((size_t)b * NB + n0) * D;
    const float* kb = k32 + ((size_t)b * HW + p0) * D;

    #pragma unroll
    for (int r = 0; r < 2; ++r) {
        int f4 = r * 256 + t;          // 0..511 over 32 rows x 16 float4
        int row = f4 >> 4, c4 = f4 & 15;
        *(float4*)&sQ[row][c4 * 4] = *(const float4*)&qb[(size_t)row * D + c4 * 4];
        *(float4*)&sK[row][c4 * 4] = *(const float4*)&kb[(size_t)row * D + c4 * 4];
    }
    __syncthreads();

    int nr = 2 * ty, pc = 2 * tx;
    float L[2][2][4] = {};
    for (int d0 = 0; d0 < 16; ++d0) {
        float4 qa = *(const float4*)&sQ[nr][d0 * 4];
        float4 qc = *(const float4*)&sQ[nr + 1][d0 * 4];
        float4 ka = *(const float4*)&sK[pc][d0 * 4];
        float4 kc = *(const float4*)&sK[pc + 1][d0 * 4];
        const float* qaf = (const float*)&qa;
        const float* qcf = (const float*)&qc;
        const float* kaf = (const float*)&ka;
        const float* kcf = (const float*)&kc;
        #pragma unroll
        for (int l = 0; l < 4; ++l) {
            L[0][0][l] = L[0][0][l] + qaf[l] * kaf[l];
            L[0][1][l] = L[0][1][l] + qaf[l] * kcf[l];
            L[1][0][l] = L[1][0][l] + qcf[l] * kaf[l];
            L[1][1][l] = L[1][1][l] + qcf[l] * kcf[l];
        }
    }
    _Float16* Sb = S16 + (size_t)b * NB * HW;
    #pragma unroll
    for (int oy = 0; oy < 2; ++oy)
        #pragma unroll
        for (int ox = 0; ox < 2; ++ox) {
            float s = (L[oy][ox][0] + L[oy][ox][1]) + (L[oy][ox][2] + L[oy][ox][3]);
            Sb[(size_t)(n0 + nr + oy) * HW + (p0 + pc + ox)] = (_Float16)s;
        }
}

// ---------------------------------------------------------------- K3: per-row top-k
// fp16 shadow selects top-NCAND; exact fp32 re-rank with the IDENTICAL SSE-order formula
__global__ __launch_bounds__(256) void k_topk(
    const _Float16* __restrict__ S16,
    const float* __restrict__ q32, const float* __restrict__ k32,
    int* __restrict__ cidx, float* __restrict__ cval, double* __restrict__ rowss) {
    __shared__ float  sc[36][256];   // 36 KB scores
    __shared__ float  wv[4];
    __shared__ int    wpp[4];
    __shared__ int    wpos;
    __shared__ int    selp[NCAND];
    __shared__ float  cv[NCAND];
    __shared__ int    cp[NCAND];
    __shared__ double ssq[TOPK];

    int t   = threadIdx.x;
    int row = blockIdx.x;            // b*NB + n
    int b = row / NB, n = row % NB;

    const _Float16* Srow = S16 + (size_t)row * HW;
    for (int i = 0; i < 36; ++i) {
        int p = i * 256 + t;
        float v = (float)Srow[p];
        int hh = p / W, ww = p - hh * W;
        if (((hh >> 2) * NBH + (ww >> 2)) == n) v = -INFINITY;   // self-block mask
        sc[i][t] = v;
    }
    __syncthreads();

    for (int pass = 0; pass < NCAND; ++pass) {
        float bv = -INFINITY; int bp = 0x7fffffff;
        #pragma unroll
        for (int i = 0; i < 36; ++i) {
            float v = sc[i][t];
            if (v > bv) { bv = v; bp = i * 256 + t; }   // strict > : smaller p wins ties
        }
        #pragma unroll
        for (int off = 32; off > 0; off >>= 1) {
            float ov = __shfl_xor(bv, off, 64);
            int   op = __shfl_xor(bp, off, 64);
            if (ov > bv || (ov == bv && op < bp)) { bv = ov; bp = op; }
        }
        if ((t & 63) == 0) { wv[t >> 6] = bv; wpp[t >> 6] = bp; }
        __syncthreads();
        if (t == 0) {
            float fv = wv[0]; int fp_ = wpp[0];
            #pragma unroll
            for (int w = 1; w < 4; ++w)
                if (wv[w] > fv || (wv[w] == fv && wpp[w] < fp_)) { fv = wv[w]; fp_ = wpp[w]; }
            selp[pass] = fp_; wpos = fp_;
        }
        __syncthreads();
        int wp = wpos;
        if ((wp & 255) == t) sc[wp >> 8][t] = -INFINITY;   // remove winner
        __syncthreads();
    }

    // exact fp32 recompute of the NCAND candidates — np.einsum SSE order, no FMA
    if (t < NCAND) {
        #pragma clang fp contract(off)
        int p = selp[t];
        const float* qr = q32 + (size_t)row * D;
        const float* kr = k32 + ((size_t)b * HW + p) * D;
        float L0 = 0.f, L1 = 0.f, L2 = 0.f, L3 = 0.f;
        #pragma unroll
        for (int j = 0; j < 16; ++j) {
            L0 = L0 + qr[4 * j + 0] * kr[4 * j + 0];
            L1 = L1 + qr[4 * j + 1] * kr[4 * j + 1];
            L2 = L2 + qr[4 * j + 2] * kr[4 * j + 2];
            L3 = L3 + qr[4 * j + 3] * kr[4 * j + 3];
        }
        cv[t] = (L0 + L1) + (L2 + L3);
        cp[t] = p;
    }
    __syncthreads();
    if (t == 0) {   // exact descending sort, tie -> smaller index (stable top_k semantics)
        for (int i = 1; i < NCAND; ++i) {
            float v = cv[i]; int p = cp[i];
            int j = i - 1;
            while (j >= 0 && (cv[j] < v || (cv[j] == v && cp[j] > p))) {
                cv[j + 1] = cv[j]; cp[j + 1] = cp[j]; --j;
            }
            cv[j + 1] = v; cp[j + 1] = p;
        }
    }
    __syncthreads();

    if (t < TK2) {
        cval[(size_t)row * TK2 + t] = cv[t];
        cidx[(size_t)row * TK2 + t] = cp[t];
    }
    if (t < TOPK) {
        double vi = (double)cv[t], s = 0.0;
        #pragma unroll
        for (int j = 0; j < TK2; ++j) { double dd = vi - (double)cv[j]; s += dd * dd; }
        ssq[t] = s;
    }
    __syncthreads();
    if (t == 0) {
        double s = 0.0;
        #pragma unroll
        for (int i = 0; i < TOPK; ++i) s += ssq[i];
        rowss[row] = s;
    }
}

// ---------------------------------------------------------------- K4: per-batch RMS -> scale
__global__ void k_rms(const double* __restrict__ rowss, double* __restrict__ scale) {
    __shared__ double sb[256];
    int b = blockIdx.x, t = threadIdx.x;
    double s = 0.0;
    for (int r = t; r < NB; r += 256) s += rowss[b * NB + r];
    sb[t] = s; __syncthreads();
    for (int st = 128; st > 0; st >>= 1) {
        if (t < st) sb[t] += sb[t + st];
        __syncthreads();
    }
    if (t == 0) {
        double rms = sqrt(sb[0] / ((double)NB * TOPK * TK2));
        scale[b] = 10.0 / (rms + 1e-3);
    }
}

// ---------------------------------------------------------------- K5: finalize — SOLE writer of d_out (float32)
__global__ __launch_bounds__(256) void k_final(
    const int* __restrict__ cidx, const float* __restrict__ cval,
    const double* __restrict__ scale, float* __restrict__ out) {
    __shared__ double sv[16][TK2];
    int t = threadIdx.x;
    int row0 = blockIdx.x * 16;
    for (int idx = t; idx < 16 * TK2; idx += 256) {
        int r = idx >> 5, j = idx & 31;
        sv[r][j] = (double)cval[(size_t)(row0 + r) * TK2 + j];
    }
    __syncthreads();
    int r = t >> 4, i = t & 15;
    int row = row0 + r;
    double scb = scale[row / NB];
    double vi = sv[r][i];
    double s = 0.0;
    #pragma unroll
    for (int j = 0; j < TK2; ++j) {
        double x = (vi - sv[r][j]) * scb;
        s += 1.0 / (1.0 + exp(-x));
    }
    // weights chunk (float32)
    out[(size_t)B * NB * TOPK + (size_t)row * TOPK + i] = (float)tanh(s - (double)TOPK);
    // index chunk (float32, exact integers)
    out[(size_t)row * TOPK + i] = (float)cidx[(size_t)row * TK2 + i];
}

// ---------------------------------------------------------------- sentinel fill (ws too small)
__global__ void k_fill(float* out, int nelem) {
    int i = blockIdx.x * 256 + threadIdx.x;
    if (i < nelem) out[i] = -12345.0f;
}

// ---------------------------------------------------------------- launch
extern "C" void kernel_launch(void* const* d_in, const int* in_sizes, int n_in,
                              void* d_out, int out_size, void* d_ws, size_t ws_size,
                              hipStream_t stream) {
    const float* src = (const float*)d_in[0];
    const float* Wq  = (const float*)d_in[1];
    const float* bq  = (const float*)d_in[2];
    const float* Wk  = (const float*)d_in[3];
    const float* bk  = (const float*)d_in[4];
    float* out = (float*)d_out;

    char* ws = (char*)d_ws;
    size_t oWkT = 0;
    size_t oWqT = oWkT + (size_t)C * D * 4;
    size_t oQ   = oWqT + (size_t)C * D * 4;
    size_t oK   = oQ   + (size_t)B * NB * D * 4;
    size_t oS   = oK   + (size_t)B * HW * D * 4;
    size_t oCV  = oS   + (size_t)B * NB * HW * 2;
    size_t oCI  = oCV  + (size_t)B * NB * TK2 * 4;
    size_t oRS  = oCI  + (size_t)B * NB * TK2 * 4;
    size_t oSc  = oRS  + (size_t)B * NB * 8;
    size_t need = oSc  + (size_t)B * 8;

    if (ws_size < need) {
        k_fill<<<(out_size + 255) / 256, 256, 0, stream>>>(out, out_size);
        return;
    }

    float*     WkT  = (float*)(ws + oWkT);
    float*     WqT  = (float*)(ws + oWqT);
    float*     q32  = (float*)(ws + oQ);
    float*     k32  = (float*)(ws + oK);
    _Float16*  S16  = (_Float16*)(ws + oS);
    float*     cval = (float*)(ws + oCV);
    int*       cidx = (int*)(ws + oCI);
    double*    rss  = (double*)(ws + oRS);
    double*    scl  = (double*)(ws + oSc);

    k_transpose<<<(C * D + 255) / 256, 256, 0, stream>>>(Wk, Wq, WkT, WqT);
    k_embed<<<B * NB, 256, 0, stream>>>(src, WkT, WqT, bk, bq, k32, q32);
    k_scores<<<dim3(HW / 32, NB / 32, B), 256, 0, stream>>>(q32, k32, S16);
    k_topk<<<B * NB, 256, 0, stream>>>(S16, q32, k32, cidx, cval, rss);
    k_rms<<<B, 256, 0, stream>>>(rss, scl);
    k_final<<<B * NB / 16, 256, 0, stream>>>(cidx, cval, scl, out);
}

// Round 6
// 656.848 us; speedup vs baseline: 1.9347x; 1.9347x over previous
//
#include <hip/hip_runtime.h>
#include <hip/hip_bf16.h>
#include <math.h>

// Problem constants
constexpr int B    = 16;
constexpr int H    = 96;
constexpr int W    = 96;
constexpr int C    = 512;
constexpr int D    = 64;
constexpr int NBH  = 24;          // blocks per side
constexpr int NB   = 576;         // num_block_tot
constexpr int HW   = 9216;
constexpr int TOPK = 16;
constexpr int TK2  = 32;          // 2*TOPK
constexpr int NCAND = 40;         // selection threshold rank (exact fp32 re-rank after)
constexpr int KC   = 384;         // OpenBLAS sgemm k-panel (confirmed by R5 pass)
constexpr int CAP  = 64;          // candidate cap (ties)

// ---------------------------------------------------------------- K0: transpose weights
__global__ void k_transpose(const float* __restrict__ Wk, const float* __restrict__ Wq,
                            float* __restrict__ WkT, float* __restrict__ WqT) {
    int idx = blockIdx.x * 256 + threadIdx.x;   // over C*D
    if (idx < C * D) {
        int c = idx >> 6, d = idx & 63;
        WkT[c * D + d] = Wk[d * C + c];
        WqT[c * D + d] = Wq[d * C + c];
    }
}

// ---------------------------------------------------------------- K1: pool + q + k, fp32 numpy-order
// NUMERICS FROZEN (R5 pass): mean sequential (dy,dx) then /16; fmaf chains split at KC=384
__global__ __launch_bounds__(256) void k_embed(
    const float* __restrict__ src,
    const float* __restrict__ WkT, const float* __restrict__ WqT,
    const float* __restrict__ bk,  const float* __restrict__ bq,
    float* __restrict__ k32, float* __restrict__ q32) {
    __shared__ float sS[16][C];    // 32 KB
    __shared__ float sE[C];        // 2 KB

    int t   = threadIdx.x;
    int blk = blockIdx.x;
    int b = blk / NB, n = blk % NB;
    int nh = n / NBH, nw = n % NBH;
    int y0 = nh * 4, x0 = nw * 4;

    for (int r = 0; r < 8; ++r) {
        int f4 = r * 256 + t;
        int px = f4 >> 7;
        int c4 = f4 & 127;
        int dy = px >> 2, dx = px & 3;
        const float4* g = (const float4*)(src + ((size_t)(b * H + y0 + dy) * W + (x0 + dx)) * C);
        ((float4*)sS[px])[c4] = g[c4];
    }
    __syncthreads();

    for (int cc = t; cc < C; cc += 256) {
        float s = sS[0][cc];
        #pragma unroll
        for (int px = 1; px < 16; ++px) s += sS[px][cc];
        sE[cc] = s * 0.0625f;
    }
    __syncthreads();

    int d = t & 63, pg = t >> 6;
    int px0 = pg * 4;
    float a0 = 0.f, a1 = 0.f, a2 = 0.f, a3 = 0.f;   // panel 0
    for (int cc = 0; cc < KC; ++cc) {
        float wk = WkT[cc * D + d];
        a0 = __builtin_fmaf(sS[px0 + 0][cc], wk, a0);
        a1 = __builtin_fmaf(sS[px0 + 1][cc], wk, a1);
        a2 = __builtin_fmaf(sS[px0 + 2][cc], wk, a2);
        a3 = __builtin_fmaf(sS[px0 + 3][cc], wk, a3);
    }
    float e0 = 0.f, e1 = 0.f, e2 = 0.f, e3 = 0.f;   // panel 1
    for (int cc = KC; cc < C; ++cc) {
        float wk = WkT[cc * D + d];
        e0 = __builtin_fmaf(sS[px0 + 0][cc], wk, e0);
        e1 = __builtin_fmaf(sS[px0 + 1][cc], wk, e1);
        e2 = __builtin_fmaf(sS[px0 + 2][cc], wk, e2);
        e3 = __builtin_fmaf(sS[px0 + 3][cc], wk, e3);
    }
    float bkd = bk[d];
    float kv0 = (a0 + e0) + bkd;
    float kv1 = (a1 + e1) + bkd;
    float kv2 = (a2 + e2) + bkd;
    float kv3 = (a3 + e3) + bkd;
    #pragma unroll
    for (int u = 0; u < 4; ++u) {
        int pxx = px0 + u;
        int dy = pxx >> 2, dx = pxx & 3;
        size_t p = (size_t)(y0 + dy) * W + (x0 + dx);
        float v = (u == 0 ? kv0 : u == 1 ? kv1 : u == 2 ? kv2 : kv3);
        k32[((size_t)b * HW + p) * D + d] = v;
    }

    if (t < 64) {
        float qa = 0.f;
        for (int cc = 0; cc < KC; ++cc)
            qa = __builtin_fmaf(sE[cc], WqT[cc * D + t], qa);
        float qe = 0.f;
        for (int cc = KC; cc < C; ++cc)
            qe = __builtin_fmaf(sE[cc], WqT[cc * D + t], qe);
        q32[((size_t)b * NB + n) * D + t] = (qa + qe) + bq[t];
    }
}

// ---------------------------------------------------------------- K2: scores SHADOW (fp16) — numerics free
// fmaf allowed here: selection margin (~0.025) >> fp16 error (~4e-3) >> fma reorder error (~1e-7)
__global__ __launch_bounds__(256) void k_scores(
    const float* __restrict__ q32, const float* __restrict__ k32,
    _Float16* __restrict__ S16) {
    __shared__ float sQ[32][68];
    __shared__ float sK[32][68];

    int t  = threadIdx.x;
    int p0 = blockIdx.x * 32;      // 288 tiles
    int n0 = blockIdx.y * 32;      // 18 tiles
    int b  = blockIdx.z;
    int tx = t & 15, ty = t >> 4;

    const float* qb = q32 + ((size_t)b * NB + n0) * D;
    const float* kb = k32 + ((size_t)b * HW + p0) * D;

    #pragma unroll
    for (int r = 0; r < 2; ++r) {
        int f4 = r * 256 + t;
        int row = f4 >> 4, c4 = f4 & 15;
        *(float4*)&sQ[row][c4 * 4] = *(const float4*)&qb[(size_t)row * D + c4 * 4];
        *(float4*)&sK[row][c4 * 4] = *(const float4*)&kb[(size_t)row * D + c4 * 4];
    }
    __syncthreads();

    int nr = 2 * ty, pc = 2 * tx;
    float acc[2][2] = {};
    for (int d0 = 0; d0 < 16; ++d0) {
        float4 qa = *(const float4*)&sQ[nr][d0 * 4];
        float4 qc = *(const float4*)&sQ[nr + 1][d0 * 4];
        float4 ka = *(const float4*)&sK[pc][d0 * 4];
        float4 kc = *(const float4*)&sK[pc + 1][d0 * 4];
        const float* qaf = (const float*)&qa;
        const float* qcf = (const float*)&qc;
        const float* kaf = (const float*)&ka;
        const float* kcf = (const float*)&kc;
        #pragma unroll
        for (int l = 0; l < 4; ++l) {
            acc[0][0] = __builtin_fmaf(qaf[l], kaf[l], acc[0][0]);
            acc[0][1] = __builtin_fmaf(qaf[l], kcf[l], acc[0][1]);
            acc[1][0] = __builtin_fmaf(qcf[l], kaf[l], acc[1][0]);
            acc[1][1] = __builtin_fmaf(qcf[l], kcf[l], acc[1][1]);
        }
    }
    _Float16* Sb = S16 + (size_t)b * NB * HW;
    #pragma unroll
    for (int oy = 0; oy < 2; ++oy) {
        _Float16 h0 = (_Float16)acc[oy][0];
        _Float16 h1 = (_Float16)acc[oy][1];
        unsigned int pack = ((unsigned int)*(unsigned short*)&h1 << 16) |
                            (unsigned int)*(unsigned short*)&h0;
        *(unsigned int*)&Sb[(size_t)(n0 + nr + oy) * HW + (p0 + pc)] = pack;
    }
}

// ---------------------------------------------------------------- K3: per-row top-k via 2-pass radix select
// mono16 transform -> high-byte histogram -> low-byte histogram -> exact 40th-value threshold ->
// gather (ties incl, cap 64) -> exact fp32 SSE-order re-rank -> parallel rank-sort
__global__ __launch_bounds__(256) void k_topk(
    const _Float16* __restrict__ S16,
    const float* __restrict__ q32, const float* __restrict__ k32,
    int* __restrict__ cidx, float* __restrict__ cval, double* __restrict__ rowss) {
    __shared__ int    hist[4][256];   // per-wave sub-histograms
    __shared__ int    sfx[256];
    __shared__ int    b0s, mAbove, thrS, gcnt;
    __shared__ int    cps[CAP];
    __shared__ float  cv[CAP];
    __shared__ int    cp[CAP];
    __shared__ float  sv[CAP];
    __shared__ int    sp[CAP];
    __shared__ double ssq[TOPK];

    int t   = threadIdx.x;
    int row = blockIdx.x;            // b*NB + n
    int b = row / NB, n = row % NB;
    int wid = t >> 6;

    #pragma unroll
    for (int w = 0; w < 4; ++w) hist[w][t] = 0;
    if (t == 0) gcnt = 0;
    __syncthreads();

    // load 36 fp16/thread (9 x ushort4, coalesced), mono-transform, mask, histogram high byte
    const unsigned short* Srow = (const unsigned short*)(S16 + (size_t)row * HW);
    unsigned int my[36];
    #pragma unroll
    for (int c = 0; c < 9; ++c) {
        ushort4 v4 = ((const ushort4*)Srow)[c * 256 + t];
        #pragma unroll
        for (int j = 0; j < 4; ++j) {
            unsigned int h = (j == 0 ? v4.x : j == 1 ? v4.y : j == 2 ? v4.z : v4.w);
            unsigned int m = (h & 0x8000u) ? (h ^ 0xFFFFu) : (h | 0x8000u);
            int p = (c * 256 + t) * 4 + j;
            int hh = p / W, ww = p - hh * W;
            if (((hh >> 2) * NBH + (ww >> 2)) == n) m = 0;   // self-block mask
            my[c * 4 + j] = m;
            atomicAdd(&hist[wid][m >> 8], 1);
        }
    }
    __syncthreads();

    // suffix scan pass 1 (high byte)
    sfx[t] = hist[0][t] + hist[1][t] + hist[2][t] + hist[3][t];
    __syncthreads();
    #pragma unroll
    for (int off = 1; off < 256; off <<= 1) {
        int v = (t + off < 256) ? sfx[t + off] : 0;
        __syncthreads();
        sfx[t] += v;
        __syncthreads();
    }
    if (sfx[t] >= NCAND && (t == 255 || sfx[t + 1] < NCAND)) {
        b0s = t; mAbove = (t == 255) ? 0 : sfx[t + 1];
    }
    __syncthreads();
    int b0 = b0s, mab = mAbove;
    __syncthreads();

    // pass 2: low byte among high byte == b0
    #pragma unroll
    for (int w = 0; w < 4; ++w) hist[w][t] = 0;
    __syncthreads();
    #pragma unroll
    for (int i = 0; i < 36; ++i)
        if ((int)(my[i] >> 8) == b0) atomicAdd(&hist[wid][my[i] & 255u], 1);
    __syncthreads();
    sfx[t] = hist[0][t] + hist[1][t] + hist[2][t] + hist[3][t];
    __syncthreads();
    #pragma unroll
    for (int off = 1; off < 256; off <<= 1) {
        int v = (t + off < 256) ? sfx[t + off] : 0;
        __syncthreads();
        sfx[t] += v;
        __syncthreads();
    }
    if (mab + sfx[t] >= NCAND && (t == 255 || mab + sfx[t + 1] < NCAND))
        thrS = (b0 << 8) | t;
    __syncthreads();
    unsigned int thr = (unsigned int)thrS;   // mono value of the 40th-largest element

    // gather all candidates with mono >= thr (includes boundary ties)
    #pragma unroll
    for (int i = 0; i < 36; ++i) {
        if (my[i] >= thr) {
            int pos = atomicAdd(&gcnt, 1);
            if (pos < CAP) {
                int c = i >> 2, j = i & 3;
                cps[pos] = (c * 256 + t) * 4 + j;
            }
        }
    }
    __syncthreads();
    int M = min(gcnt, CAP);

    // exact fp32 re-rank — np.einsum SSE order, no FMA (NUMERICS FROZEN)
    if (t < M) {
        #pragma clang fp contract(off)
        int p = cps[t];
        const float* qr = q32 + (size_t)row * D;
        const float* kr = k32 + ((size_t)b * HW + p) * D;
        float L0 = 0.f, L1 = 0.f, L2 = 0.f, L3 = 0.f;
        #pragma unroll
        for (int j = 0; j < 16; ++j) {
            L0 = L0 + qr[4 * j + 0] * kr[4 * j + 0];
            L1 = L1 + qr[4 * j + 1] * kr[4 * j + 1];
            L2 = L2 + qr[4 * j + 2] * kr[4 * j + 2];
            L3 = L3 + qr[4 * j + 3] * kr[4 * j + 3];
        }
        cv[t] = (L0 + L1) + (L2 + L3);
        cp[t] = p;
    }
    __syncthreads();

    // parallel rank-sort: desc value, tie -> smaller index (stable top_k semantics)
    if (t < M) {
        float v = cv[t]; int p = cp[t];
        int rank = 0;
        for (int j = 0; j < M; ++j) {
            float vj = cv[j];
            rank += (vj > v) || (vj == v && cp[j] < p);
        }
        sv[rank] = v; sp[rank] = p;
    }
    __syncthreads();

    if (t < TK2) {
        cval[(size_t)row * TK2 + t] = sv[t];
        cidx[(size_t)row * TK2 + t] = sp[t];
    }
    if (t < TOPK) {
        double vi = (double)sv[t], s = 0.0;
        #pragma unroll
        for (int j = 0; j < TK2; ++j) { double dd = vi - (double)sv[j]; s += dd * dd; }
        ssq[t] = s;
    }
    __syncthreads();
    if (t == 0) {
        double s = 0.0;
        #pragma unroll
        for (int i = 0; i < TOPK; ++i) s += ssq[i];
        rowss[row] = s;
    }
}

// ---------------------------------------------------------------- K4: per-batch RMS -> scale
__global__ void k_rms(const double* __restrict__ rowss, double* __restrict__ scale) {
    __shared__ double sb[256];
    int b = blockIdx.x, t = threadIdx.x;
    double s = 0.0;
    for (int r = t; r < NB; r += 256) s += rowss[b * NB + r];
    sb[t] = s; __syncthreads();
    for (int st = 128; st > 0; st >>= 1) {
        if (t < st) sb[t] += sb[t + st];
        __syncthreads();
    }
    if (t == 0) {
        double rms = sqrt(sb[0] / ((double)NB * TOPK * TK2));
        scale[b] = 10.0 / (rms + 1e-3);
    }
}

// ---------------------------------------------------------------- K5: finalize — SOLE writer of d_out (float32)
__global__ __launch_bounds__(256) void k_final(
    const int* __restrict__ cidx, const float* __restrict__ cval,
    const double* __restrict__ scale, float* __restrict__ out) {
    __shared__ double sv[16][TK2];
    int t = threadIdx.x;
    int row0 = blockIdx.x * 16;
    for (int idx = t; idx < 16 * TK2; idx += 256) {
        int r = idx >> 5, j = idx & 31;
        sv[r][j] = (double)cval[(size_t)(row0 + r) * TK2 + j];
    }
    __syncthreads();
    int r = t >> 4, i = t & 15;
    int row = row0 + r;
    double scb = scale[row / NB];
    double vi = sv[r][i];
    double s = 0.0;
    #pragma unroll
    for (int j = 0; j < TK2; ++j) {
        double x = (vi - sv[r][j]) * scb;
        s += 1.0 / (1.0 + exp(-x));
    }
    out[(size_t)B * NB * TOPK + (size_t)row * TOPK + i] = (float)tanh(s - (double)TOPK);
    out[(size_t)row * TOPK + i] = (float)cidx[(size_t)row * TK2 + i];
}

// ---------------------------------------------------------------- sentinel fill (ws too small)
__global__ void k_fill(float* out, int nelem) {
    int i = blockIdx.x * 256 + threadIdx.x;
    if (i < nelem) out[i] = -12345.0f;
}

// ---------------------------------------------------------------- launch
extern "C" void kernel_launch(void* const* d_in, const int* in_sizes, int n_in,
                              void* d_out, int out_size, void* d_ws, size_t ws_size,
                              hipStream_t stream) {
    const float* src = (const float*)d_in[0];
    const float* Wq  = (const float*)d_in[1];
    const float* bq  = (const float*)d_in[2];
    const float* Wk  = (const float*)d_in[3];
    const float* bk  = (const float*)d_in[4];
    float* out = (float*)d_out;

    char* ws = (char*)d_ws;
    size_t oWkT = 0;
    size_t oWqT = oWkT + (size_t)C * D * 4;
    size_t oQ   = oWqT + (size_t)C * D * 4;
    size_t oK   = oQ   + (size_t)B * NB * D * 4;
    size_t oS   = oK   + (size_t)B * HW * D * 4;
    size_t oCV  = oS   + (size_t)B * NB * HW * 2;
    size_t oCI  = oCV  + (size_t)B * NB * TK2 * 4;
    size_t oRS  = oCI  + (size_t)B * NB * TK2 * 4;
    size_t oSc  = oRS  + (size_t)B * NB * 8;
    size_t need = oSc  + (size_t)B * 8;

    if (ws_size < need) {
        k_fill<<<(out_size + 255) / 256, 256, 0, stream>>>(out, out_size);
        return;
    }

    float*     WkT  = (float*)(ws + oWkT);
    float*     WqT  = (float*)(ws + oWqT);
    float*     q32  = (float*)(ws + oQ);
    float*     k32  = (float*)(ws + oK);
    _Float16*  S16  = (_Float16*)(ws + oS);
    float*     cval = (float*)(ws + oCV);
    int*       cidx = (int*)(ws + oCI);
    double*    rss  = (double*)(ws + oRS);
    double*    scl  = (double*)(ws + oSc);

    k_transpose<<<(C * D + 255) / 256, 256, 0, stream>>>(Wk, Wq, WkT, WqT);
    k_embed<<<B * NB, 256, 0, stream>>>(src, WkT, WqT, bk, bq, k32, q32);
    k_scores<<<dim3(HW / 32, NB / 32, B), 256, 0, stream>>>(q32, k32, S16);
    k_topk<<<B * NB, 256, 0, stream>>>(S16, q32, k32, cidx, cval, rss);
    k_rms<<<B, 256, 0, stream>>>(rss, scl);
    k_final<<<B * NB / 16, 256, 0, stream>>>(cidx, cval, scl, out);
}